// Round 6
// baseline (314.888 us; speedup 1.0000x reference)
//
#include <hip/hip_runtime.h>

#define M_DIM 4096
#define N_DIM 4096
#define K_DIM 4096

typedef float f32x4 __attribute__((ext_vector_type(4)));
typedef __bf16 bf16x8 __attribute__((ext_vector_type(8)));

// round-to-nearest-even fp32 -> bf16
__device__ __forceinline__ unsigned short f2b(float f) {
    unsigned int u = __float_as_uint(f);
    u += 0x7fffu + ((u >> 16) & 1u);
    return (unsigned short)(u >> 16);
}

// Arithmetic NVFP4 (e2m1) decode — pure VALU, bit-exact vs the codebook.
__device__ __forceinline__ float nvfp4_decode(int n) {
    unsigned m = (unsigned)n & 7u;
    unsigned e = m >> 1, f = m & 1u;
    unsigned bits = (m >= 2u) ? (((126u + e) << 23) | (f << 22))
                              : (m * 0x3f000000u);   // 0 -> 0.0f, 1 -> 0.5f
    bits |= ((unsigned)n & 8u) << 28;                 // sign
    return __uint_as_float(bits);
}

// ---------------------------------------------------------------------------
// Prep: separate high-occupancy streaming kernels (proven ~31us total =
// traffic roofline).
// ---------------------------------------------------------------------------
__global__ __launch_bounds__(256) void xconv_kernel(
        const float* __restrict__ x, unsigned short* __restrict__ xb) {
    size_t i = ((size_t)blockIdx.x * 256 + threadIdx.x) * 8;
    float4 a0 = *(const float4*)(x + i);
    float4 a1 = *(const float4*)(x + i + 4);
    union { unsigned short h[8]; uint4 u; } o;
    o.h[0] = f2b(a0.x); o.h[1] = f2b(a0.y); o.h[2] = f2b(a0.z); o.h[3] = f2b(a0.w);
    o.h[4] = f2b(a1.x); o.h[5] = f2b(a1.y); o.h[6] = f2b(a1.z); o.h[7] = f2b(a1.w);
    *(uint4*)(xb + i) = o.u;
}

__global__ __launch_bounds__(256) void wbuild_kernel(
        const int* __restrict__ idx4, const float* __restrict__ sc4,
        const float* __restrict__ gs4, const float* __restrict__ w8,
        const float* __restrict__ s8, const float* __restrict__ w16,
        const int* __restrict__ iperm, unsigned short* __restrict__ W) {
    const int j = blockIdx.x;
    const int t = threadIdx.x;
    const int g = iperm[j];

#pragma unroll
    for (int h = 0; h < 2; ++h) {
        const int k0 = h * 2048 + t * 8;   // 8 elems / thread / half
        union { unsigned short hh[8]; uint4 u; } o;
        if (g < 2048) {
            const float s = sc4[(size_t)g * (K_DIM / 16) + (k0 >> 4)] * gs4[0];
            const int4* ip = (const int4*)(idx4 + (size_t)g * K_DIM + k0);
            int4 v0 = ip[0], v1 = ip[1];
            o.hh[0] = f2b(nvfp4_decode(v0.x) * s);
            o.hh[1] = f2b(nvfp4_decode(v0.y) * s);
            o.hh[2] = f2b(nvfp4_decode(v0.z) * s);
            o.hh[3] = f2b(nvfp4_decode(v0.w) * s);
            o.hh[4] = f2b(nvfp4_decode(v1.x) * s);
            o.hh[5] = f2b(nvfp4_decode(v1.y) * s);
            o.hh[6] = f2b(nvfp4_decode(v1.z) * s);
            o.hh[7] = f2b(nvfp4_decode(v1.w) * s);
        } else if (g < 3072) {
            const float s = s8[0];
            const float4* wp = (const float4*)(w8 + (size_t)(g - 2048) * K_DIM + k0);
            float4 v0 = wp[0], v1 = wp[1];
            o.hh[0] = f2b(v0.x * s); o.hh[1] = f2b(v0.y * s);
            o.hh[2] = f2b(v0.z * s); o.hh[3] = f2b(v0.w * s);
            o.hh[4] = f2b(v1.x * s); o.hh[5] = f2b(v1.y * s);
            o.hh[6] = f2b(v1.z * s); o.hh[7] = f2b(v1.w * s);
        } else {
            const float4* wp = (const float4*)(w16 + (size_t)(g - 3072) * K_DIM + k0);
            float4 v0 = wp[0], v1 = wp[1];
            o.hh[0] = f2b(v0.x); o.hh[1] = f2b(v0.y);
            o.hh[2] = f2b(v0.z); o.hh[3] = f2b(v0.w);
            o.hh[4] = f2b(v1.x); o.hh[5] = f2b(v1.y);
            o.hh[6] = f2b(v1.z); o.hh[7] = f2b(v1.w);
        }
        *(uint4*)(W + (size_t)j * K_DIM + k0) = o.u;
    }
}

// ---------------------------------------------------------------------------
// GEMM: C[M,N] = Xb[M,K] * Wb[N,K]^T + bias
// R6: occupancy attack. R4/R5 showed LDS-drain and MFMA-burst strictly SUM
// when 1 block/CU (8 lockstep waves). New geometry gives 2 independent
// blocks/CU so one block's LDS reads overlap the other's MFMAs:
//   tile 256x128, BK=32, 8 waves (4M x 2N), 64x64 per wave
//   -> acc 64 VGPR, total ~110 VGPR -> 4 waves/SIMD (launch_bounds(512,4))
//   -> LDS 3 slots x 24KB = 72KB/block, 2 blocks = 144KB/CU
// Per wave per K-tile: 3 gloads (stage T+2), 8 ds_read_b128, 16 MFMA.
// Counted vmcnt(3) at tile end (T4): T+1's stages drained, T+2's stay in
// flight across the barrier. Per-SIMD demand: MFMA 77.6cy vs LDS 64cy per
// wave-tile -> balanced, MFMA-bound when overlapped.
//
// Frag/staging/swizzle math = R4's proven zero-conflict scheme verbatim:
// 1KB subtile = 16 rows x 32 bf16; st_16x32 (chunk bit1 ^= row bit3);
// stage via inverse-swizzled global source + linear LDS dest;
// read addr inner = ((l16<<6)|(quad<<4)) ^ ((l16&8)<<2).
//
// Rotation: tile t lives in slot t%3. Tile t's KTILE stages t+2 into slot
// (t+2)%3 (WAR-safe: that slot's last reads were tile t-1, barrier-ordered).
// vmcnt(3) leaves exactly the 3 newest (T+2) loads in flight; T+1's data is
// complete+visible after the barrier. Loop = 42 x 3 tiles + 2 tail tiles
// (their stage targets wrap to dead slots).
// ---------------------------------------------------------------------------
#define GLOAD_LDS16(g, l)                                                     \
    __builtin_amdgcn_global_load_lds(                                         \
        (const __attribute__((address_space(1))) void*)(unsigned long long)(g),\
        (__attribute__((address_space(3))) void*)(unsigned int)(unsigned long long)(l), \
        16, 0, 0)

// stage tile tn (wrapped) into slot: 3 subtile gloads (2 A + 1 B) per wave
#define STAGE_TILE(slot, tn) do {                                             \
    const int _kt = (tn) & 127;                                               \
    GLOAD_LDS16(pA0 + (size_t)_kt * 32, smem + (slot) * 24576 + dA0);         \
    GLOAD_LDS16(pA1 + (size_t)_kt * 32, smem + (slot) * 24576 + dA1);         \
    GLOAD_LDS16(pB0 + (size_t)_kt * 32, smem + (slot) * 24576 + dB0);         \
} while (0)

#define READFRAGS(slot) do {                                                  \
    _Pragma("unroll") for (int mi = 0; mi < 4; ++mi)                          \
        af[mi] = *(const bf16x8*)(smem + (slot) * 24576 + vA + mi * 1024);    \
    _Pragma("unroll") for (int nj = 0; nj < 4; ++nj)                          \
        bq[nj] = *(const bf16x8*)(smem + (slot) * 24576 + vB + nj * 1024);    \
} while (0)

#define MMA16 do {                                                            \
    _Pragma("unroll") for (int nj = 0; nj < 4; ++nj)                          \
        _Pragma("unroll") for (int mi = 0; mi < 4; ++mi)                      \
            acc[mi][nj] = __builtin_amdgcn_mfma_f32_16x16x32_bf16(            \
                af[mi], bq[nj], acc[mi][nj], 0, 0, 0);                        \
} while (0)

#define BARRIER __builtin_amdgcn_s_barrier()
#define WAIT_VM3 asm volatile("s_waitcnt vmcnt(3)" ::: "memory")
#define SCHED_FENCE __builtin_amdgcn_sched_barrier(0)
#define PRIO1 __builtin_amdgcn_s_setprio(1)
#define PRIO0 __builtin_amdgcn_s_setprio(0)

#define KTILE(slot, sslot, tn) do {                                           \
    STAGE_TILE(sslot, tn);                                                    \
    READFRAGS(slot);                                                          \
    PRIO1; MMA16; PRIO0;                                                      \
    WAIT_VM3;                                                                 \
    BARRIER;                                                                  \
    SCHED_FENCE;                                                              \
} while (0)

__global__ __launch_bounds__(512, 4) void gemm_kernel(
        const unsigned short* __restrict__ X, const unsigned short* __restrict__ W,
        const float* __restrict__ bias, float* __restrict__ C) {
    __shared__ __align__(1024) unsigned char smem[73728];   // 3 x 24KB

    // XCD-aware chunked swizzle: 512 blocks, 8 XCDs, 64 contiguous wgs each
    const int pid = blockIdx.x;
    const int wg = (pid & 7) * 64 + (pid >> 3);
    const int bm = wg >> 5, bn = wg & 31;      // 16 x 32 tiles
    const int m0 = bm * 256, n0 = bn * 128;

    const int tid  = threadIdx.x;
    const int wave = tid >> 6;       // 0..7
    const int lane = tid & 63;
    const int wr   = wave >> 1;      // 0..3  (M quarter, 64 rows)
    const int wc   = wave & 1;       // 0..1  (N half, 64 cols)
    const int l16  = lane & 15;
    const int quad = lane >> 4;

    // ---- staging: per-lane global source (inverse st_16x32 swizzle) ----
    const int srow   = lane >> 2;                          // 0..15 in subtile
    const int schunk = (lane & 3) ^ ((lane >> 5) << 1);    // chunk b1 ^= row b3

    // wave owns A subtiles {2w, 2w+1} (rows m0+wave*32..+31) and B subtile w
    const unsigned short* pA0 = X + (size_t)(m0 + wave * 32 + srow) * K_DIM + schunk * 8;
    const unsigned short* pA1 = pA0 + (size_t)16 * K_DIM;
    const unsigned short* pB0 = W + (size_t)(n0 + wave * 16 + srow) * K_DIM + schunk * 8;

    const int dA0 = (wave * 2) * 1024 + lane * 16;         // linear LDS dest
    const int dA1 = dA0 + 1024;
    const int dB0 = 16384 + wave * 1024 + lane * 16;

    // ---- fragment read addressing (swizzled, R4-proven) ----
    const int inner = ((l16 << 6) | (quad << 4)) ^ ((l16 & 8) << 2);
    const int vA = wr * 4096 + inner;            // + mi*1024
    const int vB = 16384 + wc * 4096 + inner;    // + nj*1024

    f32x4 acc[4][4] = {};
    bf16x8 af[4], bq[4];

    // ---- prologue: stage tiles 0,1 into slots 0,1; drain tile 0 ----
    STAGE_TILE(0, 0);
    STAGE_TILE(1, 1);
    WAIT_VM3;
    BARRIER;
    SCHED_FENCE;

#pragma unroll 1
    for (int t = 0; t < 126; t += 3) {
        KTILE(0, 2, t + 2);
        KTILE(1, 0, t + 3);
        KTILE(2, 1, t + 4);
    }
    KTILE(0, 2, 0);   // tile 126 (stage target dead)
    KTILE(1, 0, 1);   // tile 127 (stage target dead)

    // ---- epilogue: C/D layout col=lane&15, row=quad*4+reg ----
    const int crow0 = m0 + wr * 64 + quad * 4;
    const int ccol0 = n0 + wc * 64 + l16;
    float bv[4];
#pragma unroll
    for (int p = 0; p < 4; ++p) bv[p] = bias[ccol0 + p * 16];
#pragma unroll
    for (int mi = 0; mi < 4; ++mi) {
#pragma unroll
        for (int nj = 0; nj < 4; ++nj) {
            const int col = ccol0 + nj * 16;
            const int rowb = crow0 + mi * 16;
#pragma unroll
            for (int r = 0; r < 4; ++r)
                C[(size_t)(rowb + r) * N_DIM + col] = acc[mi][nj][r] + bv[nj];
        }
    }
}

// ---------------------------------------------------------------------------
extern "C" void kernel_launch(void* const* d_in, const int* in_sizes, int n_in,
                              void* d_out, int out_size, void* d_ws, size_t ws_size,
                              hipStream_t stream) {
    const float* x            = (const float*)d_in[0];
    const int*   nvfp4_idx    = (const int*)d_in[1];
    const float* nvfp4_scales = (const float*)d_in[2];
    const float* gscale       = (const float*)d_in[3];
    const float* w_fp8        = (const float*)d_in[4];
    const float* fp8_scale    = (const float*)d_in[5];
    const float* w_fp16       = (const float*)d_in[6];
    const float* bias         = (const float*)d_in[7];
    const int*   inv_perm     = (const int*)d_in[8];
    float* out = (float*)d_out;

    unsigned short* xb = (unsigned short*)d_ws;                 // 32 MiB
    unsigned short* wb = xb + (size_t)M_DIM * K_DIM;            // 32 MiB

    xconv_kernel<<<8192, 256, 0, stream>>>(x, xb);
    wbuild_kernel<<<4096, 256, 0, stream>>>(nvfp4_idx, nvfp4_scales, gscale,
                                            w_fp8, fp8_scale, w_fp16,
                                            inv_perm, wb);
    gemm_kernel<<<(M_DIM / 256) * (N_DIM / 128), 512, 0, stream>>>(xb, wb, bias, out);
}